// Round 5
// baseline (360.819 us; speedup 1.0000x reference)
//
#include <hip/hip_runtime.h>
#include <hip/hip_bf16.h>
#include <cstdint>
#include <cstddef>

// ---- constants (fixed by the reference problem) ----
#define Hh 1024
#define D_EMB 512
#define D_UP 2048
#define BT 16384      // B*T
#define BB_ 512
#define Mm 4096
#define MmP 4160      // Mm + 64 pad cols for chunk-tail overreads (VT zero-padded)
#define NB 32         // BT/BB
#define KL 64         // K_LABELS
#define NXCD 8

typedef __attribute__((ext_vector_type(4))) float f4;
typedef __attribute__((ext_vector_type(4))) __bf16 bf4;
typedef __attribute__((ext_vector_type(8))) __bf16 bf8;
typedef __attribute__((ext_vector_type(4))) float f32x4;

// ---------------- helpers ----------------
__device__ __forceinline__ void gl_lds16(const void* g, void* l) {
  __builtin_amdgcn_global_load_lds((__attribute__((address_space(1))) void*)g,
                                   (__attribute__((address_space(3))) void*)l, 16, 0, 0);
}

// ---------------- prep kernels ----------------
__global__ __launch_bounds__(256) void conv_bf16_kernel(const float* __restrict__ src,
                                                        __bf16* __restrict__ dst, int n4) {
  int i = blockIdx.x * 256 + threadIdx.x;
  if (i >= n4) return;
  f4 v = ((const f4*)src)[i];
  bf4 o = {(__bf16)v[0], (__bf16)v[1], (__bf16)v[2], (__bf16)v[3]};
  ((bf4*)dst)[i] = o;
}

__global__ __launch_bounds__(256) void gather_bf16_kernel(const float* __restrict__ src,
                                                          const int* __restrict__ idx,
                                                          __bf16* __restrict__ dst, int cols4) {
  int row = blockIdx.x;
  const f4* s = (const f4*)src + (size_t)idx[row] * cols4;
  bf4* d = (bf4*)dst + (size_t)row * cols4;
  for (int i = threadIdx.x; i < cols4; i += 256) {
    f4 v = s[i];
    bf4 o = {(__bf16)v[0], (__bf16)v[1], (__bf16)v[2], (__bf16)v[3]};
    d[i] = o;
  }
}

__global__ __launch_bounds__(256) void la_kernel(const int* __restrict__ keep,
                                                 const int* __restrict__ emb,
                                                 int* __restrict__ la, int m) {
  int i = blockIdx.x * 256 + threadIdx.x;
  if (i < m) la[i] = emb[keep[i]];
}

__global__ __launch_bounds__(256) void range_kernel(const int* __restrict__ starts,
                                                    const int* __restrict__ ends,
                                                    int* __restrict__ stA, int* __restrict__ enA) {
  int n = blockIdx.x;
  int t = threadIdx.x, lane = t & 63, wv = t >> 6;
  int s1 = min(starts[n * BB_ + t], starts[n * BB_ + t + 256]);
  int e1 = max(ends[n * BB_ + t], ends[n * BB_ + t + 256]);
#pragma unroll
  for (int off = 32; off; off >>= 1) {
    s1 = min(s1, __shfl_xor(s1, off));
    e1 = max(e1, __shfl_xor(e1, off));
  }
  __shared__ int ssh[4], esh[4];
  if (lane == 0) { ssh[wv] = s1; esh[wv] = e1; }
  __syncthreads();
  if (t == 0) {
    int s = ssh[0], e = esh[0];
#pragma unroll
    for (int k = 1; k < 4; ++k) { s = min(s, ssh[k]); e = max(e, esh[k]); }
    stA[n] = s; enA[n] = e;
  }
}

// histogram of labels over all Mm rows + exclusive prefix -> goff[KL+1]
__global__ __launch_bounds__(256) void hist_kernel(const int* __restrict__ la,
                                                   int* __restrict__ goff) {
  __shared__ int cnt[KL];
  int tid = threadIdx.x;
  if (tid < KL) cnt[tid] = 0;
  __syncthreads();
  for (int k = tid; k < Mm; k += 256) atomicAdd(&cnt[la[k]], 1);
  __syncthreads();
  if (tid == 0) {
    int a = 0;
    for (int s = 0; s < KL; ++s) { goff[s] = a; a += cnt[s]; }
    goff[KL] = a;
  }
}

// stable placement: global sorted-by-(label,k) order. one wg per label.
__global__ __launch_bounds__(256) void place_kernel(const int* __restrict__ la,
                                                    const int* __restrict__ keep,
                                                    const int* __restrict__ goff,
                                                    int* __restrict__ gk,
                                                    int* __restrict__ ridx) {
  int s = blockIdx.x;
  int tid = threadIdx.x, lane = tid & 63, wv = tid >> 6;
  __shared__ int wc[4];
  __shared__ int run;
  if (tid == 0) run = goff[s];
  __syncthreads();
  for (int base = 0; base < Mm; base += 256) {
    int k = base + tid;
    bool f = (la[k] == s);
    unsigned long long msk = __ballot(f);
    int myidx = __popcll(msk & ((1ull << lane) - 1ull));
    if (lane == 0) wc[wv] = __popcll(msk);
    __syncthreads();
    int woff = 0, tot = 0;
#pragma unroll
    for (int w = 0; w < 4; ++w) {
      if (w < wv) woff += wc[w];
      tot += wc[w];
    }
    int rbase = run;
    if (f) {
      int p = rbase + woff + myidx;
      gk[p] = k;
      ridx[p] = keep[k];
    }
    __syncthreads();
    if (tid == 0) run = rbase + tot;
    __syncthreads();
  }
}

// per (block,label): contiguous sorted-pos range [lo,hi)
__global__ __launch_bounds__(256) void lohi_kernel(const int* __restrict__ gk,
                                                   const int* __restrict__ goff,
                                                   const int* __restrict__ stA,
                                                   const int* __restrict__ enA,
                                                   int* __restrict__ loA, int* __restrict__ hiA) {
  int i = blockIdx.x * 256 + threadIdx.x;
  if (i >= NB * KL) return;
  int n = i / KL, s = i % KL;
  int b = goff[s], e = goff[s + 1];
  int st = stA[n], en = enA[n];
  int lo = b, hi = e;
  while (lo < hi) { int mid = (lo + hi) >> 1; if (gk[mid] < st) lo = mid + 1; else hi = mid; }
  int L = lo;
  lo = b; hi = e;
  while (lo < hi) { int mid = (lo + hi) >> 1; if (gk[mid] < en) lo = mid + 1; else hi = mid; }
  loA[i] = L;
  hiA[i] = lo;
}

// VT[d][pos] = bf16(w_v[ridx[pos]][d]) via LDS tile transpose; zero pad pos>=Mm
__global__ __launch_bounds__(256) void vt_kernel(const float* __restrict__ wv_,
                                                 const int* __restrict__ ridx,
                                                 __bf16* __restrict__ VT) {
  int pb = blockIdx.x * 64;
  int db = blockIdx.y * 64;
  __shared__ float T[64][65];
  int t = threadIdx.x;
  int dl = t & 63, g = t >> 6;
  for (int i = g * 16; i < g * 16 + 16; ++i) {
    int pos = pb + i;
    float val = 0.f;
    if (pos < Mm) {
      int r = ridx[pos];
      val = wv_[(size_t)r * D_EMB + db + dl];
    }
    T[dl][i] = val;
  }
  __syncthreads();
  int pl = t & 63;
  for (int j = g * 16; j < g * 16 + 16; ++j) {
    VT[(size_t)(db + j) * MmP + pb + pl] = (__bf16)T[j][pl];
  }
}

// counting sort of queries by label within each block of 512
__global__ __launch_bounds__(256) void qsort_kernel(const int* __restrict__ seq_sort,
                                                    int* __restrict__ qidx,
                                                    int* __restrict__ qoffA,
                                                    int* __restrict__ qcntA) {
  int n = blockIdx.x, tid = threadIdx.x;
  __shared__ int cnt[KL], pos[KL], pref[KL];
  if (tid < KL) cnt[tid] = 0;
  __syncthreads();
  int s0 = seq_sort[n * BB_ + tid];
  int s1 = seq_sort[n * BB_ + tid + 256];
  atomicAdd(&cnt[s0], 1);
  atomicAdd(&cnt[s1], 1);
  __syncthreads();
  if (tid == 0) {
    int a = 0;
    for (int s = 0; s < KL; ++s) { pref[s] = a; a += cnt[s]; }
  }
  __syncthreads();
  if (tid < KL) {
    pos[tid] = pref[tid];
    qoffA[n * KL + tid] = pref[tid];
    qcntA[n * KL + tid] = cnt[tid];
  }
  __syncthreads();
  int p0 = atomicAdd(&pos[s0], 1);
  qidx[n * BB_ + p0] = n * BB_ + tid;
  int p1 = atomicAdd(&pos[s1], 1);
  qidx[n * BB_ + p1] = n * BB_ + tid + 256;
}

// ---------------- RMSNorm of input (single read, scatter via bw) ----------------
// row j: inb[j] = bf16(input[j]); Aperm[bw[j]] = bf16(rms(input[j]) * w)  (fw[bw[j]] = j)
__global__ __launch_bounds__(256) void rms_in_kernel(const float* __restrict__ input,
                                                     const int* __restrict__ bw,
                                                     const float* __restrict__ wn,
                                                     __bf16* __restrict__ Aperm,
                                                     __bf16* __restrict__ inb) {
  int wv = threadIdx.x >> 6, lane = threadIdx.x & 63;
  int j = blockIdx.x * 4 + wv;
  const f4* src = (const f4*)(input + (size_t)j * Hh);
  f4 v[4];
  float ss = 0.f;
#pragma unroll
  for (int c = 0; c < 4; ++c) {
    v[c] = src[c * 64 + lane];
    ss += v[c][0] * v[c][0] + v[c][1] * v[c][1] + v[c][2] * v[c][2] + v[c][3] * v[c][3];
  }
#pragma unroll
  for (int off = 32; off; off >>= 1) ss += __shfl_xor(ss, off);
  float sc = rsqrtf(ss * (1.f / Hh) + 1e-6f);
  bf4* dstI = (bf4*)(inb + (size_t)j * Hh);
#pragma unroll
  for (int c = 0; c < 4; ++c) {
    bf4 o = {(__bf16)v[c][0], (__bf16)v[c][1], (__bf16)v[c][2], (__bf16)v[c][3]};
    dstI[c * 64 + lane] = o;
  }
  int dj = bw[j];
  const f4* w4 = (const f4*)wn;
  bf4* dstA = (bf4*)(Aperm + (size_t)dj * Hh);
#pragma unroll
  for (int c = 0; c < 4; ++c) {
    f4 w = w4[c * 64 + lane];
    bf4 o = {(__bf16)(v[c][0] * sc * w[0]), (__bf16)(v[c][1] * sc * w[1]),
             (__bf16)(v[c][2] * sc * w[2]), (__bf16)(v[c][3] * sc * w[3])};
    dstA[c * 64 + lane] = o;
  }
}

// ---------------- wave-per-group attention, zero barriers ----------------
// Swapped QK^T: mfma(K,Q) -> C[kv][q], lane owns q=lane&15 (16 kv per lane).
// Softmax per-lane + 2 shfl_xor. P repacked in-register to PV B-frags via shfl.
// Swapped PV: mfma(VT_row, P) -> C[d][q]. Epilogue via per-wave LDS transpose.
__global__ __launch_bounds__(256, 2) void attn4_kernel(const __bf16* __restrict__ Aperm,
                                                       const __bf16* __restrict__ Ks,
                                                       const __bf16* __restrict__ VT,
                                                       const int* __restrict__ qidx,
                                                       const int* __restrict__ qoffA,
                                                       const int* __restrict__ qcntA,
                                                       const int* __restrict__ loA,
                                                       const int* __restrict__ hiA,
                                                       const int* __restrict__ fw,
                                                       __bf16* __restrict__ comb) {
  __shared__ __align__(16) __bf16 owb[4][16][528];
  int wv = threadIdx.x >> 6, lane = threadIdx.x & 63;
  int g = blockIdx.x * 4 + wv;
  int qcnt = qcntA[g];
  int lo = loA[g], hi = hiA[g];
  if (qcnt == 0 || lo >= hi) return;
  int n = g >> 6;
  int qbase = n * BB_ + qoffA[g];
  int c = lane & 15, rg = lane >> 4;
  int sl_a = c + ((rg & 1) << 5);  // source lane for i=0..3 of repack
  int sl_b = sl_a + 16;            // source lane for i=4..7
  bool hiKt = (rg & 2) != 0;
  const __bf16* vbase = VT + (size_t)c * MmP + rg * 8;

  for (int qt = 0; qt < qcnt; qt += 16) {
    int ql = qt + c;
    int j = qidx[qbase + (ql < qcnt ? ql : qcnt - 1)];
    const __bf16* qrow = Aperm + (size_t)j * Hh + rg * 8;

    float m = -1e30f, lsum = 0.f;
    f32x4 acc[32];
    f32x4 zero = {0.f, 0.f, 0.f, 0.f};
#pragma unroll
    for (int ff = 0; ff < 32; ++ff) acc[ff] = zero;

    for (int p0 = lo; p0 < hi; p0 += 64) {
      // ---- QK^T (swapped): sN[kt] = C[kv-tile kt][q] ----
      const __bf16* kb = Ks + (size_t)(p0 + c) * Hh + rg * 8;
      f32x4 sN[4];
#pragma unroll
      for (int kt = 0; kt < 4; ++kt) sN[kt] = zero;
#pragma unroll
      for (int ks = 0; ks < 32; ++ks) {
        bf8 qf = *(const bf8*)(qrow + ks * 32);
#pragma unroll
        for (int kt = 0; kt < 4; ++kt) {
          bf8 kf = *(const bf8*)(kb + (size_t)kt * 16 * Hh + ks * 32);
          sN[kt] = __builtin_amdgcn_mfma_f32_16x16x32_bf16(kf, qf, sN[kt], 0, 0, 0);
        }
      }
      // ---- mask + per-lane online softmax (lane owns q=c, 16 kv) ----
      float smax = -1e30f;
#pragma unroll
      for (int kt = 0; kt < 4; ++kt)
#pragma unroll
        for (int r = 0; r < 4; ++r) {
          int kv = p0 + kt * 16 + rg * 4 + r;
          float sv = (kv < hi) ? sN[kt][r] : -1e30f;
          sN[kt][r] = sv;
          smax = fmaxf(smax, sv);
        }
      smax = fmaxf(smax, __shfl_xor(smax, 16));
      smax = fmaxf(smax, __shfl_xor(smax, 32));
      float mn = fmaxf(m, smax);
      float sc = __expf(m - mn);
      float sum = 0.f;
#pragma unroll
      for (int kt = 0; kt < 4; ++kt)
#pragma unroll
        for (int r = 0; r < 4; ++r) {
          float pv = __expf(sN[kt][r] - mn);
          sN[kt][r] = pv;
          sum += pv;
        }
      sum += __shfl_xor(sum, 16);
      sum += __shfl_xor(sum, 32);
      lsum = lsum * sc + sum;
      m = mn;
#pragma unroll
      for (int ff = 0; ff < 32; ++ff) acc[ff] = acc[ff] * sc;

      // ---- repack P to PV B-frags: lane needs P[q][32h + rg*8 + i] ----
      bf8 pbh[2];
#pragma unroll
      for (int h = 0; h < 2; ++h) {
        float e[8];
#pragma unroll
        for (int r = 0; r < 4; ++r) {
          float a0 = __shfl(sN[2 * h][r], sl_a);
          float a1 = __shfl(sN[2 * h + 1][r], sl_a);
          e[r] = hiKt ? a1 : a0;
          float b0 = __shfl(sN[2 * h][r], sl_b);
          float b1 = __shfl(sN[2 * h + 1][r], sl_b);
          e[4 + r] = hiKt ? b1 : b0;
        }
        bf8 pb;
#pragma unroll
        for (int i = 0; i < 8; ++i) pb[i] = (__bf16)e[i];
        pbh[h] = pb;
      }
      // ---- PV (swapped): acc[ff] = C[d-tile ff][q] ----
#pragma unroll
      for (int ff = 0; ff < 32; ++ff) {
        const __bf16* vr = vbase + (size_t)ff * (16 * MmP) + p0;
        bf8 v0 = *(const bf8*)(vr);
        bf8 v1 = *(const bf8*)(vr + 32);
        acc[ff] = __builtin_amdgcn_mfma_f32_16x16x32_bf16(v0, pbh[0], acc[ff], 0, 0, 0);
        acc[ff] = __builtin_amdgcn_mfma_f32_16x16x32_bf16(v1, pbh[1], acc[ff], 0, 0, 0);
      }
    }

    // ---- epilogue: normalize, per-wave LDS transpose, coalesced store ----
    float inv = 1.f / lsum;
#pragma unroll
    for (int ff = 0; ff < 32; ++ff) {
      bf4 o;
#pragma unroll
      for (int r = 0; r < 4; ++r) o[r] = (__bf16)(acc[ff][r] * inv);
      *(bf4*)&owb[wv][c][ff * 16 + rg * 4] = o;
    }
    int qp = qt + (lane >> 2);
    bool vq = qp < qcnt;
    size_t ob = 0;
    if (vq) ob = (size_t)fw[qidx[qbase + qp]] * D_EMB + (lane & 3) * 8;
#pragma unroll
    for (int it = 0; it < 16; ++it) {
      bf8 o = *(const bf8*)&owb[wv][lane >> 2][(lane & 3) * 8 + it * 32];
      if (vq) *(bf8*)(comb + ob + (size_t)it * 32) = o;
    }
  }
}

// ---------------- 256x256 phase-pipelined GEMM: C = X @ W^T ----------------
template <bool OUT_BF16>
__global__ __launch_bounds__(512, 2) void gemm8p(const __bf16* __restrict__ x0, int k0,
                                                 const __bf16* __restrict__ x1, int k1,
                                                 const __bf16* __restrict__ w,
                                                 void* __restrict__ outp, int Mt, int Nt) {
  __shared__ __align__(16) __bf16 lds[4][2][256 * 32];  // [buf][A/B][row*32+col]
  const int nwg = Mt * Nt;
  const int bid = blockIdx.x;
  const int swz = (bid % NXCD) * (nwg / NXCD) + bid / NXCD;
  const int m0 = (swz / Nt) * 256, n0 = (swz % Nt) * 256;
  const int K = k0 + k1;
  const int NT = K >> 5;
  const int N = Nt * 256;
  const int tid = threadIdx.x, lane = tid & 63, wvi = tid >> 6;
  const int wr = wvi >> 2, wc = wvi & 3;

  const int srow = tid >> 2;
  const int spb = (tid & 3) * 16;

  const int c = lane & 15, rg = lane >> 4;
  const int fa_off = c * 64 + ((rg ^ ((c >> 1) & 3)) << 4);

  auto stage_half = [&](int t, int j) {
    int kg = t * 32;
    const __bf16* xs;
    int ld, kk;
    if (kg < k0) { xs = x0; ld = k0; kk = kg; }
    else         { xs = x1; ld = k1; kk = kg - k0; }
    int b = t & 3;
    int r = j * 128 + srow;
    int lcol = (spb ^ (((r >> 1) & 3) << 4)) >> 1;
    gl_lds16(xs + (size_t)(m0 + r) * ld + kk + lcol,
             (void*)((char*)&lds[b][0][0] + r * 64 + spb));
    gl_lds16(w + (size_t)(n0 + r) * K + kg + lcol,
             (void*)((char*)&lds[b][1][0] + r * 64 + spb));
  };

  f32x4 acc[8][4];
  f32x4 zero = {0.f, 0.f, 0.f, 0.f};
#pragma unroll
  for (int a = 0; a < 8; ++a)
#pragma unroll
    for (int bnx = 0; bnx < 4; ++bnx) acc[a][bnx] = zero;

#pragma unroll
  for (int t = 0; t < 3; ++t) {
    stage_half(t, 0);
    stage_half(t, 1);
  }
  asm volatile("s_waitcnt vmcnt(8)" ::: "memory");
  __builtin_amdgcn_s_barrier();

  for (int t = 0; t < NT; ++t) {
    const char* Abase = (const char*)&lds[t & 3][0][0];
    const char* Bbase = (const char*)&lds[t & 3][1][0];
    bf8 bfr[4];
#pragma unroll
    for (int ri = 0; ri < 2; ++ri) {
      if (t + 3 < NT) stage_half(t + 3, ri);
      bf8 afr[4];
#pragma unroll
      for (int fi = 0; fi < 4; ++fi)
        afr[fi] = *(const bf8*)(Abase + (wr * 128 + ri * 64 + fi * 16) * 64 + fa_off);
      if (ri == 0) {
#pragma unroll
        for (int fi = 0; fi < 4; ++fi)
          bfr[fi] = *(const bf8*)(Bbase + (wc * 64 + fi * 16) * 64 + fa_off);
      }
      __builtin_amdgcn_s_barrier();
      __builtin_amdgcn_s_setprio(1);
#pragma unroll
      for (int fi = 0; fi < 4; ++fi)
#pragma unroll
        for (int ni = 0; ni < 4; ++ni)
          acc[ri * 4 + fi][ni] =
              __builtin_amdgcn_mfma_f32_16x16x32_bf16(afr[fi], bfr[ni], acc[ri * 4 + fi][ni], 0, 0, 0);
      __builtin_amdgcn_s_setprio(0);
      if (ri == 1) asm volatile("s_waitcnt vmcnt(8)" ::: "memory");
      __builtin_amdgcn_s_barrier();
    }
  }

  const int r0 = (lane >> 4) * 4, cc = lane & 15;
#pragma unroll
  for (int mi = 0; mi < 8; ++mi) {
    int rowb = m0 + wr * 128 + (mi >> 2) * 64 + (mi & 3) * 16 + r0;
#pragma unroll
    for (int ni = 0; ni < 4; ++ni) {
      int col = n0 + wc * 64 + ni * 16 + cc;
#pragma unroll
      for (int r = 0; r < 4; ++r) {
        float v = acc[mi][ni][r];
        if (OUT_BF16)
          ((__bf16*)outp)[(size_t)(rowb + r) * N + col] = (__bf16)v;
        else
          ((float*)outp)[(size_t)(rowb + r) * N + col] = v;
      }
    }
  }
}

// ---------------- in-place RMSNorm of up ----------------
__global__ __launch_bounds__(256) void rms_up_kernel(__bf16* __restrict__ up,
                                                     const float* __restrict__ wn) {
  int wv = threadIdx.x >> 6, lane = threadIdx.x & 63;
  size_t j = (size_t)blockIdx.x * 4 + wv;
  bf8* row = (bf8*)(up + j * D_UP);
  bf8 v[4];
  float ss = 0.f;
#pragma unroll
  for (int c = 0; c < 4; ++c) {
    v[c] = row[c * 64 + lane];
#pragma unroll
    for (int i = 0; i < 8; ++i) { float f = (float)v[c][i]; ss += f * f; }
  }
#pragma unroll
  for (int off = 32; off; off >>= 1) ss += __shfl_xor(ss, off);
  float sc = rsqrtf(ss * (1.f / D_UP) + 1e-6f);
#pragma unroll
  for (int c = 0; c < 4; ++c) {
    int ebase = (c * 64 + lane) * 8;
    f4 wa = *(const f4*)(wn + ebase);
    f4 wb = *(const f4*)(wn + ebase + 4);
    bf8 o;
#pragma unroll
    for (int i = 0; i < 4; ++i) o[i] = (__bf16)((float)v[c][i] * sc * wa[i]);
#pragma unroll
    for (int i = 0; i < 4; ++i) o[4 + i] = (__bf16)((float)v[c][4 + i] * sc * wb[i]);
    row[c * 64 + lane] = o;
  }
}

// ---------------- launch ----------------
extern "C" void kernel_launch(void* const* d_in, const int* in_sizes, int n_in, void* d_out,
                              int out_size, void* d_ws, size_t ws_size, hipStream_t stream) {
  const float* input = (const float*)d_in[0];
  const int* fw = (const int*)d_in[1];
  const int* bw = (const int*)d_in[2];
  const int* seq_sort = (const int*)d_in[3];
  const int* keep_cols = (const int*)d_in[4];
  const int* emb_alloc = (const int*)d_in[5];
  const int* starts = (const int*)d_in[6];
  const int* ends = (const int*)d_in[7];
  const float* w_k = (const float*)d_in[9];
  const float* w_v = (const float*)d_in[10];
  const float* w_up = (const float*)d_in[11];
  const float* w_mix = (const float*)d_in[12];
  const float* w_nin = (const float*)d_in[13];
  const float* w_nout = (const float*)d_in[14];

  char* p = (char*)d_ws;
  auto take = [&](size_t b) {
    void* r = (void*)p;
    p += (b + 255) & ~(size_t)255;
    return r;
  };
  __bf16* Aperm = (__bf16*)take((size_t)BT * Hh * 2);
  __bf16* inb = (__bf16*)take((size_t)BT * Hh * 2);
  __bf16* comb = (__bf16*)take((size_t)BT * D_EMB * 2);
  __bf16* up = (__bf16*)take((size_t)BT * D_UP * 2);
  __bf16* Ks = (__bf16*)take((size_t)MmP * Hh * 2);
  __bf16* VT = (__bf16*)take((size_t)D_EMB * MmP * 2);
  __bf16* wupB = (__bf16*)take((size_t)D_UP * D_EMB * 2);
  __bf16* wmixB = (__bf16*)take((size_t)Hh * (D_UP + Hh) * 2);
  int* la = (int*)take(Mm * 4);
  int* stA = (int*)take(NB * 4);
  int* enA = (int*)take(NB * 4);
  int* goff = (int*)take((KL + 1) * 4);
  int* gk = (int*)take(Mm * 4);
  int* ridx = (int*)take(Mm * 4);
  int* loA = (int*)take(NB * KL * 4);
  int* hiA = (int*)take(NB * KL * 4);
  int* qidx = (int*)take(BT * 4);
  int* qoffA = (int*)take(NB * KL * 4);
  int* qcntA = (int*)take(NB * KL * 4);

  // prep
  conv_bf16_kernel<<<(D_UP * D_EMB / 4 + 255) / 256, 256, 0, stream>>>(w_up, wupB, D_UP * D_EMB / 4);
  conv_bf16_kernel<<<(Hh * (D_UP + Hh) / 4 + 255) / 256, 256, 0, stream>>>(w_mix, wmixB,
                                                                           Hh * (D_UP + Hh) / 4);
  la_kernel<<<Mm / 256, 256, 0, stream>>>(keep_cols, emb_alloc, la, Mm);
  range_kernel<<<NB, 256, 0, stream>>>(starts, ends, stA, enA);
  hist_kernel<<<1, 256, 0, stream>>>(la, goff);
  place_kernel<<<KL, 256, 0, stream>>>(la, keep_cols, goff, gk, ridx);
  lohi_kernel<<<(NB * KL + 255) / 256, 256, 0, stream>>>(gk, goff, stA, enA, loA, hiA);
  gather_bf16_kernel<<<Mm, 256, 0, stream>>>(w_k, ridx, Ks, Hh / 4);
  vt_kernel<<<dim3(MmP / 64, D_EMB / 64), 256, 0, stream>>>(w_v, ridx, VT);
  qsort_kernel<<<NB, 256, 0, stream>>>(seq_sort, qidx, qoffA, qcntA);

  // pipeline
  rms_in_kernel<<<BT / 4, 256, 0, stream>>>(input, bw, w_nin, Aperm, inb);
  attn4_kernel<<<NB * KL / 4, 256, 0, stream>>>(Aperm, Ks, VT, qidx, qoffA, qcntA, loA, hiA, fw,
                                                comb);
  gemm8p<true><<<BT / 256 * (D_UP / 256), 512, 0, stream>>>(comb, D_EMB, (const __bf16*)nullptr, 0,
                                                            wupB, (void*)up, BT / 256, D_UP / 256);
  rms_up_kernel<<<BT / 4, 256, 0, stream>>>(up, w_nout);
  gemm8p<false><<<BT / 256 * (Hh / 256), 512, 0, stream>>>(up, D_UP, inb, Hh, wmixB, d_out,
                                                           BT / 256, Hh / 256);
}